// Round 5
// baseline (20345.197 us; speedup 1.0000x reference)
//
#include <hip/hip_runtime.h>
#include <stdint.h>

// BiGRU scan, H=1024. Round 5: per-wave register gather + atomic-swap publish.
//  - Publish: fire-and-forget global_atomic_exchange (executes AT the LLC ->
//    minimal remote visibility latency; tests the store-drain hypothesis).
//  - Gather: each lane polls the 8 16B granules (2l+j+128i) holding exactly
//    the x slots (k=4l+256i+m) its weight registers need. No LDS, no
//    intra-block sync; each wave advances when its own granules are fresh.
//  - q-chain de-folded onto its own 128 blocks (256 total, 1 block/CU).
//  - Tag invariant: publisher of tag t+2 requires all waves consumed tag t,
//    so a fresh granule is never overwritten mid-gather (2-parity window).

#define H    1024
#define HH   1025
#define N3   3075
#define TQ   512
#define TP   4096
#define MTOT 4608
#define GH_ELEMS ((size_t)MTOT * (size_t)N3)
#define NBLK_P 128
#define NBLK_Q 128

typedef unsigned long long ull;
typedef unsigned int u32x4 __attribute__((ext_vector_type(4)));

__device__ __forceinline__ float sigm(float x) { return 1.f / (1.f + __expf(-x)); }
__device__ __forceinline__ float fast_tanh(float x) {
    float e = __expf(2.f * x);
    return (e - 1.f) / (e + 1.f);
}

__device__ __forceinline__ void load8g(const ull* p0, const ull* p1, const ull* p2, const ull* p3,
                                       const ull* p4, const ull* p5, const ull* p6, const ull* p7,
                                       u32x4& a0, u32x4& a1, u32x4& a2, u32x4& a3,
                                       u32x4& a4, u32x4& a5, u32x4& a6, u32x4& a7) {
    asm volatile(
        "global_load_dwordx4 %0, %8, off sc0 sc1\n\t"
        "global_load_dwordx4 %1, %9, off sc0 sc1\n\t"
        "global_load_dwordx4 %2, %10, off sc0 sc1\n\t"
        "global_load_dwordx4 %3, %11, off sc0 sc1\n\t"
        "global_load_dwordx4 %4, %12, off sc0 sc1\n\t"
        "global_load_dwordx4 %5, %13, off sc0 sc1\n\t"
        "global_load_dwordx4 %6, %14, off sc0 sc1\n\t"
        "global_load_dwordx4 %7, %15, off sc0 sc1\n\t"
        "s_waitcnt vmcnt(0)"
        : "=&v"(a0), "=&v"(a1), "=&v"(a2), "=&v"(a3),
          "=&v"(a4), "=&v"(a5), "=&v"(a6), "=&v"(a7)
        : "v"(p0), "v"(p1), "v"(p2), "v"(p3), "v"(p4), "v"(p5), "v"(p6), "v"(p7)
        : "memory");
}

// ---------------------------------------------------------------------------
// gh GEMM (unchanged): gh[dir][m][r] = h0[m][dir] . Whh_dir[r] + bhh_dir[r]
// ---------------------------------------------------------------------------
__global__ __launch_bounds__(256, 2) void gh_gemm(
    const float* __restrict__ eq, const float* __restrict__ ep,
    const float* __restrict__ fs, const float* __restrict__ fe,
    const float* __restrict__ Whh_f, const float* __restrict__ bhh_f,
    const float* __restrict__ Whh_b, const float* __restrict__ bhh_b,
    float* __restrict__ ghf, float* __restrict__ ghb)
{
    const int dir = blockIdx.z;
    const float* W  = dir ? Whh_b : Whh_f;
    const float* bh = dir ? bhh_b : bhh_f;
    float* gh = dir ? ghb : ghf;
    const int n0 = blockIdx.x * 128;
    const int m0 = blockIdx.y * 128;

    __shared__ float As[16][132];
    __shared__ float Bs[16][132];

    float acc[8][8];
#pragma unroll
    for (int i = 0; i < 8; i++)
#pragma unroll
        for (int j = 0; j < 8; j++) acc[i][j] = 0.f;

    const int tid = threadIdx.x;
    const int tx = tid & 15, ty = tid >> 4;

    for (int k0 = 0; k0 < HH; k0 += 16) {
#pragma unroll
        for (int u = 0; u < 8; u++) {
            int lin = tid + 256 * u;
            int k = lin & 15;
            int m = lin >> 4;
            int gm = m0 + m;
            int gk = k0 + k;
            float v = 0.f;
            if (gk < HH) {
                bool isq = gm < TQ;
                const float* e = isq ? eq : ep;
                int t = isq ? gm : gm - TQ;
                if (dir == 0)            v = e[(size_t)t * 2048 + gk];
                else if (gk < 1023)      v = e[(size_t)t * 2048 + 1025 + gk];
                else if (!isq)           v = (gk == 1023) ? fs[t] : fe[t];
            }
            As[k][m] = v;
        }
#pragma unroll
        for (int u = 0; u < 8; u++) {
            int lin = tid + 256 * u;
            int k = lin & 15;
            int r = lin >> 4;
            int gr = n0 + r, gk = k0 + k;
            Bs[k][r] = (gr < N3 && gk < HH) ? W[(size_t)gr * HH + gk] : 0.f;
        }
        __syncthreads();
#pragma unroll
        for (int kk = 0; kk < 16; kk++) {
            float4 a0 = *(const float4*)&As[kk][ty * 4];
            float4 a1 = *(const float4*)&As[kk][64 + ty * 4];
            float4 b0 = *(const float4*)&Bs[kk][tx * 4];
            float4 b1 = *(const float4*)&Bs[kk][64 + tx * 4];
            float a[8] = {a0.x, a0.y, a0.z, a0.w, a1.x, a1.y, a1.z, a1.w};
            float b[8] = {b0.x, b0.y, b0.z, b0.w, b1.x, b1.y, b1.z, b1.w};
#pragma unroll
            for (int i = 0; i < 8; i++)
#pragma unroll
                for (int j = 0; j < 8; j++) acc[i][j] += a[i] * b[j];
        }
        __syncthreads();
    }
#pragma unroll
    for (int i = 0; i < 8; i++) {
        int gm = m0 + ((i < 4) ? (ty * 4 + i) : (64 + ty * 4 + i - 4));
#pragma unroll
        for (int j = 0; j < 8; j++) {
            int gr = n0 + ((j < 4) ? (tx * 4 + j) : (64 + tx * 4 + j - 4));
            if (gr < N3) gh[(size_t)gm * N3 + gr] = acc[i][j] + bh[gr];
        }
    }
}

// ---------------------------------------------------------------------------
// Persistent scan. Blocks [0,128): p-chain; [128,256): q-chain.
// Wave owns units u0,u0+1 (4 elems, 12 Wih rows; block 127 wave 3 adds the
// store-only yb[1023] elem).
// ---------------------------------------------------------------------------
__global__ __launch_bounds__(256, 1) void bigru_scan(
    const float* __restrict__ eq, const float* __restrict__ ep,
    const float* __restrict__ fs,
    const float* __restrict__ Wih_f, const float* __restrict__ bih_f,
    const float* __restrict__ Wih_b, const float* __restrict__ bih_b,
    const float* __restrict__ ghf,   // ghb contiguous at ghf + GH_ELEMS
    ull* __restrict__ comm,          // [chain p|q][parity][1024] tagged x slots
    float* __restrict__ out)         // h_q (512*2048) then h_p (4096*2048)
{
    const int tid  = threadIdx.x;
    const int wave = tid >> 6;
    const int lane = tid & 63;
    const bool isP = (int)blockIdx.x < NBLK_P;
    const int  blk = isP ? (int)blockIdx.x : (int)blockIdx.x - NBLK_P;
    const int  u0  = __builtin_amdgcn_readfirstlane(blk * 8 + wave * 2);
    const bool extra = (u0 == 1022);
    const int  nT  = isP ? TP : TQ;
    const float* emb = isP ? ep : eq;
    const float* fsp = isP ? fs : nullptr;
    ull*   cm   = comm + (isP ? 0 : 2048);
    float* outb = isP ? (out + (size_t)TQ * 2048) : out;
    const int ghTok0 = isP ? TQ : 0;

    // elems: e0=(0,u0); e1= u0? (1,u0-1):(0,1024); e2=(0,u0+1); e3=(1,u0)
    int dirE[4], rowE[4];
    bool stE1;
    dirE[0] = 0; rowE[0] = u0;
    if (u0 == 0) { dirE[1] = 0; rowE[1] = 1024;   stE1 = false; }
    else         { dirE[1] = 1; rowE[1] = u0 - 1; stE1 = true;  }
    dirE[2] = 0; rowE[2] = u0 + 1;
    dirE[3] = 1; rowE[3] = u0;

    // register-resident Wih rows (k-split: lane l holds k = 4l + 256i + m)
    float wreg[12][16], breg[12];
#pragma unroll
    for (int e = 0; e < 4; e++) {
        const float* W  = dirE[e] ? Wih_b : Wih_f;
        const float* bb = dirE[e] ? bih_b : bih_f;
#pragma unroll
        for (int g = 0; g < 3; g++) {
            const float* wr = W + (size_t)(g * HH + rowE[e]) * H;
#pragma unroll
            for (int i = 0; i < 4; i++) {
                float4 w4 = *(const float4*)(wr + i * 256 + lane * 4);
                wreg[e*3+g][i*4+0] = w4.x; wreg[e*3+g][i*4+1] = w4.y;
                wreg[e*3+g][i*4+2] = w4.z; wreg[e*3+g][i*4+3] = w4.w;
            }
            breg[e*3+g] = bb[g * HH + rowE[e]];
        }
    }
    float wregX[3][16], bregX[3];
    if (extra) {
#pragma unroll
        for (int g = 0; g < 3; g++) {
            const float* wr = Wih_b + (size_t)(g * HH + 1023) * H;
#pragma unroll
            for (int i = 0; i < 4; i++) {
                float4 w4 = *(const float4*)(wr + i * 256 + lane * 4);
                wregX[g][i*4+0] = w4.x; wregX[g][i*4+1] = w4.y;
                wregX[g][i*4+2] = w4.z; wregX[g][i*4+3] = w4.w;
            }
            bregX[g] = bih_b[g * HH + 1023];
        }
    }

    // wave-uniform gh/h0 offsets
    size_t ghoff[4];
    int h0col[4];
#pragma unroll
    for (int e = 0; e < 4; e++) {
        ghoff[e] = (dirE[e] ? GH_ELEMS : (size_t)0) + (size_t)rowE[e];
        h0col[e] = dirE[e] ? (1025 + rowE[e]) : rowE[e];   // all owned dir1 rows <=1022
    }
    const size_t ghoffX = GH_ELEMS + 1023;

    auto ldgh = [&](int tok, float gh[12], float h0[4], float ghX[3], float& h0X) {
        size_t tb = (size_t)(ghTok0 + tok) * N3;
#pragma unroll
        for (int e = 0; e < 4; e++) {
#pragma unroll
            for (int g = 0; g < 3; g++)
                gh[e*3+g] = ghf[ghoff[e] + tb + (size_t)g * HH];
            h0[e] = emb[(size_t)tok * 2048 + h0col[e]];
        }
        if (extra) {
#pragma unroll
            for (int g = 0; g < 3; g++) ghX[g] = ghf[ghoffX + tb + (size_t)g * HH];
            h0X = fsp ? fsp[tok] : 0.f;
        }
    };

    // per-lane granule byte offsets: granule(k) = 2*lane + (k&1) + 128*(k>>1)
    int gofs[8];
#pragma unroll
    for (int k = 0; k < 8; k++)
        gofs[k] = 16 * (2 * lane + (k & 1) + 128 * (k >> 1));

    float ghc[12], h0c[4], ghcX[3]; float h0X = 0.f;
    ldgh(0, ghc, h0c, ghcX, h0X);

    for (int t = 0; t < nT; t++) {
        // prefetch next step's gh/h0 (scalar path, consumed next iteration)
        float ghn[12], h0n[4], ghnX[3]; float h0nX = 0.f;
        const bool more = (t + 1) < nT;
        if (more) ldgh(t + 1, ghn, h0n, ghnX, h0nX);

        float x[16];
        if (t) {
            const unsigned tag = (unsigned)t;
            const char* rb = (const char*)(cm + (size_t)((t + 1) & 1) * 1024);
            const ull* p[8];
#pragma unroll
            for (int k = 0; k < 8; k++) p[k] = (const ull*)(rb + gofs[k]);
            u32x4 g0, g1, g2, g3, g4, g5, g6, g7;
            load8g(p[0], p[1], p[2], p[3], p[4], p[5], p[6], p[7],
                   g0, g1, g2, g3, g4, g5, g6, g7);
            for (;;) {
                bool ok = (g0[1] == tag) & (g0[3] == tag) & (g1[1] == tag) & (g1[3] == tag) &
                          (g2[1] == tag) & (g2[3] == tag) & (g3[1] == tag) & (g3[3] == tag) &
                          (g4[1] == tag) & (g4[3] == tag) & (g5[1] == tag) & (g5[3] == tag) &
                          (g6[1] == tag) & (g6[3] == tag) & (g7[1] == tag) & (g7[3] == tag);
                if (ok) break;
                load8g(p[0], p[1], p[2], p[3], p[4], p[5], p[6], p[7],
                       g0, g1, g2, g3, g4, g5, g6, g7);
            }
            x[0]  = __uint_as_float(g0[0]); x[1]  = __uint_as_float(g0[2]);
            x[2]  = __uint_as_float(g1[0]); x[3]  = __uint_as_float(g1[2]);
            x[4]  = __uint_as_float(g2[0]); x[5]  = __uint_as_float(g2[2]);
            x[6]  = __uint_as_float(g3[0]); x[7]  = __uint_as_float(g3[2]);
            x[8]  = __uint_as_float(g4[0]); x[9]  = __uint_as_float(g4[2]);
            x[10] = __uint_as_float(g5[0]); x[11] = __uint_as_float(g5[2]);
            x[12] = __uint_as_float(g6[0]); x[13] = __uint_as_float(g6[2]);
            x[14] = __uint_as_float(g7[0]); x[15] = __uint_as_float(g7[2]);
        } else {
#pragma unroll
            for (int k = 0; k < 16; k++) x[k] = 0.f;
        }

        // dots + butterfly reduce
        float acc[12], accX[3];
#pragma unroll
        for (int r = 0; r < 12; r++) {
            float s = 0.f;
#pragma unroll
            for (int i = 0; i < 16; i++) s += wreg[r][i] * x[i];
            acc[r] = s;
        }
        if (extra) {
#pragma unroll
            for (int g = 0; g < 3; g++) {
                float s = 0.f;
#pragma unroll
                for (int i = 0; i < 16; i++) s += wregX[g][i] * x[i];
                accX[g] = s;
            }
        }
#pragma unroll
        for (int off = 32; off > 0; off >>= 1) {
#pragma unroll
            for (int r = 0; r < 12; r++) acc[r] += __shfl_xor(acc[r], off, 64);
            if (extra) {
#pragma unroll
                for (int g = 0; g < 3; g++) accX[g] += __shfl_xor(accX[g], off, 64);
            }
        }

        // gates (redundant across lanes)
        float y[4];
#pragma unroll
        for (int e = 0; e < 4; e++) {
            float rr = sigm(acc[e*3+0] + breg[e*3+0] + ghc[e*3+0]);
            float zz = sigm(acc[e*3+1] + breg[e*3+1] + ghc[e*3+1]);
            float nn = fast_tanh(acc[e*3+2] + breg[e*3+2] + rr * ghc[e*3+2]);
            y[e] = (1.f - zz) * nn + zz * h0c[e];
        }

        if (lane == 0) {
            // publish first: fire-and-forget atomic swaps (execute at LLC)
            ull* ps = cm + (size_t)(t & 1) * 1024;
            const ull tg = ((ull)(unsigned)(t + 1)) << 32;
            ull v0 = tg | (ull)__float_as_uint(y[0] + y[1]);
            ull v1 = tg | (ull)__float_as_uint(y[2] + y[3]);
            (void)__hip_atomic_exchange(&ps[u0],     v0, __ATOMIC_RELAXED, __HIP_MEMORY_SCOPE_AGENT);
            (void)__hip_atomic_exchange(&ps[u0 + 1], v1, __ATOMIC_RELAXED, __HIP_MEMORY_SCOPE_AGENT);

            // out stores (off the critical path)
            size_t ob = (size_t)t * 2048;
            outb[ob + u0]        = y[0];
            outb[ob + u0 + 1]    = y[2];
            if (stE1) outb[ob + 1023 + u0] = y[1];
            outb[ob + 1024 + u0] = y[3];
            if (extra) {
                float rr = sigm(accX[0] + bregX[0] + ghcX[0]);
                float zz = sigm(accX[1] + bregX[1] + ghcX[1]);
                float nn = fast_tanh(accX[2] + bregX[2] + rr * ghcX[2]);
                outb[ob + 2047] = (1.f - zz) * nn + zz * h0X;
            }
        }

        if (more) {
#pragma unroll
            for (int r = 0; r < 12; r++) ghc[r] = ghn[r];
#pragma unroll
            for (int e = 0; e < 4; e++) h0c[e] = h0n[e];
#pragma unroll
            for (int g = 0; g < 3; g++) ghcX[g] = ghnX[g];
            h0X = h0nX;
        }
    }
}

extern "C" void kernel_launch(void* const* d_in, const int* in_sizes, int n_in,
                              void* d_out, int out_size, void* d_ws, size_t ws_size,
                              hipStream_t stream) {
    const float* eq    = (const float*)d_in[0];
    const float* ep    = (const float*)d_in[1];
    const float* fs    = (const float*)d_in[2];
    const float* fe    = (const float*)d_in[3];
    const float* Wih_f = (const float*)d_in[4];
    const float* Whh_f = (const float*)d_in[5];
    const float* bih_f = (const float*)d_in[6];
    const float* bhh_f = (const float*)d_in[7];
    const float* Wih_b = (const float*)d_in[8];
    const float* Whh_b = (const float*)d_in[9];
    const float* bih_b = (const float*)d_in[10];
    const float* bhh_b = (const float*)d_in[11];
    float* out = (float*)d_out;

    float* ghf = (float*)d_ws;
    float* ghb = ghf + GH_ELEMS;
    size_t commOff = ((2 * GH_ELEMS * sizeof(float)) + 4095) & ~(size_t)4095;
    ull* comm = (ull*)((char*)d_ws + commOff);

    // 2 chains x 2 parities x 1024 tagged slots
    hipMemsetAsync(comm, 0, (size_t)4 * 1024 * sizeof(ull), stream);

    dim3 ggrid((N3 + 127) / 128, MTOT / 128, 2);
    gh_gemm<<<ggrid, 256, 0, stream>>>(eq, ep, fs, fe, Whh_f, bhh_f, Whh_b, bhh_b, ghf, ghb);

    bigru_scan<<<dim3(NBLK_P + NBLK_Q), dim3(256), 0, stream>>>(
        eq, ep, fs, Wih_f, bih_f, Wih_b, bih_b, ghf, comm, out);
}